// Round 1
// baseline (1431.885 us; speedup 1.0000x reference)
//
#include <hip/hip_runtime.h>
#include <math.h>

#define NN 100000
#define NE 3200000

// ---------------- CSR build ----------------

__global__ __launch_bounds__(256) void k_zero_deg(int* deg) {
    int i = blockIdx.x * blockDim.x + threadIdx.x;
    if (i < NN) deg[i] = 0;
}

__global__ __launch_bounds__(256) void k_count(const int* __restrict__ dst, int* __restrict__ deg) {
    int e = blockIdx.x * blockDim.x + threadIdx.x;
    if (e < NE) atomicAdd(&deg[dst[e]], 1);
}

__global__ __launch_bounds__(1024) void k_scan_blocks(const int* __restrict__ deg,
                                                      int* __restrict__ row_off,
                                                      int* __restrict__ blk) {
    __shared__ int s[1024];
    int i = blockIdx.x * 1024 + threadIdx.x;
    int v = (i < NN) ? deg[i] : 0;
    s[threadIdx.x] = v;
    __syncthreads();
    // Hillis-Steele inclusive scan
    for (int off = 1; off < 1024; off <<= 1) {
        int t = (threadIdx.x >= off) ? s[threadIdx.x - off] : 0;
        __syncthreads();
        s[threadIdx.x] += t;
        __syncthreads();
    }
    if (i < NN) row_off[i] = s[threadIdx.x] - v;   // exclusive
    if (threadIdx.x == 1023) blk[blockIdx.x] = s[1023];
}

__global__ __launch_bounds__(64) void k_scan_tops(const int* __restrict__ blk,
                                                  int* __restrict__ blk_off, int nb) {
    if (threadIdx.x == 0 && blockIdx.x == 0) {
        int run = 0;
        for (int b = 0; b < nb; b++) { int t = blk[b]; blk_off[b] = run; run += t; }
    }
}

__global__ __launch_bounds__(256) void k_finalize(const int* __restrict__ deg,
                                                  int* __restrict__ row_off,
                                                  const int* __restrict__ blk_off,
                                                  int* __restrict__ cursor,
                                                  float* __restrict__ dis) {
    int i = blockIdx.x * blockDim.x + threadIdx.x;
    if (i < NN) {
        int r = row_off[i] + blk_off[i >> 10];
        row_off[i] = r;
        cursor[i]  = r;
        dis[i] = rsqrtf((float)deg[i] + 1.0f);  // deg over A+I
    }
}

__global__ __launch_bounds__(256) void k_fill(const int* __restrict__ src,
                                              const int* __restrict__ dst,
                                              const float* __restrict__ dis,
                                              int* __restrict__ cursor,
                                              int2* __restrict__ csr) {
    int e = blockIdx.x * blockDim.x + threadIdx.x;
    if (e < NE) {
        int s = src[e], d = dst[e];
        int pos = atomicAdd(&cursor[d], 1);
        float w = dis[s] * dis[d];
        csr[pos] = make_int2(s, __float_as_int(w));
    }
}

// ---------------- node-dense kernels ----------------

// h0 = sigmoid(x@W_pre+b_pre); ni = relu(h0@W_fc1+b_fc1); h = relu(h0@W_fc2+b_fc2)
// one thread per (node, channel); the 10-dim h0 is recomputed per thread (cheap).
__global__ __launch_bounds__(256) void k_preproc(const float* __restrict__ x,
                                                 const float* __restrict__ W_pre, const float* __restrict__ b_pre,
                                                 const float* __restrict__ W_fc1, const float* __restrict__ b_fc1,
                                                 const float* __restrict__ W_fc2, const float* __restrict__ b_fc2,
                                                 float* __restrict__ ni, float* __restrict__ h) {
    int t = blockIdx.x * blockDim.x + threadIdx.x;
    int n = t >> 5, c = t & 31;
    if (n >= NN) return;
    float xv[6];
#pragma unroll
    for (int k = 0; k < 6; k++) xv[k] = x[n * 6 + k];
    float p[10];
#pragma unroll
    for (int j = 0; j < 10; j++) {
        float a = b_pre[j];
#pragma unroll
        for (int k = 0; k < 6; k++) a += xv[k] * W_pre[k * 10 + j];
        p[j] = 1.0f / (1.0f + expf(-a));
    }
    float a1 = b_fc1[c], a2 = b_fc2[c];
#pragma unroll
    for (int j = 0; j < 10; j++) {
        a1 += p[j] * W_fc1[j * 32 + c];
        a2 += p[j] * W_fc2[j * 32 + c];
    }
    ni[n * 32 + c] = fmaxf(a1, 0.0f);
    h[n * 32 + c]  = fmaxf(a2, 0.0f);
}

// g = h @ W_gcn  (no bias here; bias+relu in gather)
__global__ __launch_bounds__(256) void k_transform(const float* __restrict__ h,
                                                   const float* __restrict__ Wg,
                                                   float* __restrict__ g) {
    __shared__ float sW[32 * 32];
    int tid = threadIdx.x;
    for (int i = tid; i < 1024; i += 256) sW[i] = Wg[i];
    __syncthreads();
    int t = blockIdx.x * 256 + tid;
    int n = t >> 5, c = t & 31;
    if (n >= NN) return;
    float acc = 0.0f;
#pragma unroll
    for (int k = 0; k < 32; k++) acc += h[n * 32 + k] * sW[k * 32 + c];
    g[n * 32 + c] = acc;
}

// t_out[n] = relu( sum_{e into n} g[src_e]*norm_e + g[n]*dis[n]^2 + b_gcn )
// one 32-lane half-wave per node; lane = channel.
__global__ __launch_bounds__(256) void k_gather(const float* __restrict__ g,
                                                const int2* __restrict__ csr,
                                                const int* __restrict__ row_off,
                                                const int* __restrict__ deg,
                                                const float* __restrict__ dis,
                                                const float* __restrict__ b_gcn,
                                                float* __restrict__ t_out) {
    int t = blockIdx.x * blockDim.x + threadIdx.x;
    int n = t >> 5, lane = threadIdx.x & 31;
    if (n >= NN) return;
    float d = dis[n];
    float acc = g[n * 32 + lane] * (d * d);   // self-loop term
    int start = row_off[n], cnt = deg[n];
    for (int base = 0; base < cnt; base += 32) {
        int idx = base + lane;
        int2 ev = make_int2(0, 0);
        if (idx < cnt) ev = csr[start + idx];
        int m = min(32, cnt - base);
        for (int j = 0; j < m; j++) {
            int   sj = __shfl(ev.x, j, 32);
            float wj = __int_as_float(__shfl(ev.y, j, 32));
            acc += g[sj * 32 + lane] * wj;     // coalesced 128B row load
        }
    }
    t_out[n * 32 + lane] = fmaxf(acc + b_gcn[lane], 0.0f);
}

// out = relu( concat(ni, hin) @ W + b ),  W is [64][32]
__global__ __launch_bounds__(256) void k_dense(const float* __restrict__ ni,
                                               const float* __restrict__ hin,
                                               const float* __restrict__ W,
                                               const float* __restrict__ b,
                                               float* __restrict__ out) {
    __shared__ float sW[64 * 32];
    __shared__ float sb[32];
    int tid = threadIdx.x;
    for (int i = tid; i < 2048; i += 256) sW[i] = W[i];
    if (tid < 32) sb[tid] = b[tid];
    __syncthreads();
    int t = blockIdx.x * 256 + tid;
    int n = t >> 5, j = tid & 31;
    if (n >= NN) return;
    float acc = sb[j];
#pragma unroll
    for (int k = 0; k < 32; k++) acc += ni[n * 32 + k] * sW[k * 32 + j];
#pragma unroll
    for (int k = 0; k < 32; k++) acc += hin[n * 32 + k] * sW[(32 + k) * 32 + j];
    out[n * 32 + j] = fmaxf(acc, 0.0f);
}

// logits = u @ W_f2 + b_f2,  W_f2 is [32][2]
__global__ __launch_bounds__(256) void k_out(const float* __restrict__ u,
                                             const float* __restrict__ W,
                                             const float* __restrict__ b,
                                             float* __restrict__ out) {
    int t = blockIdx.x * blockDim.x + threadIdx.x;
    int n = t >> 1, o = t & 1;
    if (n >= NN) return;
    float acc = b[o];
#pragma unroll
    for (int k = 0; k < 32; k++) acc += u[n * 32 + k] * W[k * 2 + o];
    out[n * 2 + o] = acc;
}

// ---------------- launch ----------------

extern "C" void kernel_launch(void* const* d_in, const int* in_sizes, int n_in,
                              void* d_out, int out_size, void* d_ws, size_t ws_size,
                              hipStream_t stream) {
    const float* x      = (const float*)d_in[0];
    const int*   ei     = (const int*)d_in[1];
    const float* W_pre  = (const float*)d_in[2];
    const float* b_pre  = (const float*)d_in[3];
    const float* W_fc1  = (const float*)d_in[4];
    const float* b_fc1  = (const float*)d_in[5];
    const float* W_fc2  = (const float*)d_in[6];
    const float* b_fc2  = (const float*)d_in[7];
    const float* W_gcn  = (const float*)d_in[8];
    const float* b_gcn  = (const float*)d_in[9];
    const float* W_dense= (const float*)d_in[10];
    const float* b_dense= (const float*)d_in[11];
    const float* W_f1   = (const float*)d_in[12];
    const float* b_f1   = (const float*)d_in[13];
    const float* W_f2   = (const float*)d_in[14];
    const float* b_f2   = (const float*)d_in[15];

    const int* src = ei;
    const int* dst = ei + NE;

    size_t off = 0;
    auto alloc = [&](size_t bytes) -> void* {
        off = (off + 255) & ~(size_t)255;
        void* p = (char*)d_ws + off;
        off += bytes;
        return p;
    };
    int*   deg     = (int*)  alloc(NN * sizeof(int));
    int*   row_off = (int*)  alloc(NN * sizeof(int));
    int*   cursor  = (int*)  alloc(NN * sizeof(int));
    int*   blk     = (int*)  alloc(128 * sizeof(int));
    int*   blk_off = (int*)  alloc(128 * sizeof(int));
    float* dis     = (float*)alloc(NN * sizeof(float));
    int2*  csr     = (int2*) alloc((size_t)NE * sizeof(int2));
    float* ni      = (float*)alloc((size_t)NN * 32 * sizeof(float));
    float* h       = (float*)alloc((size_t)NN * 32 * sizeof(float));
    float* g       = (float*)alloc((size_t)NN * 32 * sizeof(float));
    float* tbuf    = (float*)alloc((size_t)NN * 32 * sizeof(float));

    const int nodeBlocks  = (NN + 255) / 256;          // 391
    const int edgeBlocks  = (NE + 255) / 256;          // 12500
    const int ncBlocks    = (NN * 32) / 256;           // 12500
    const int scanBlocks  = (NN + 1023) / 1024;        // 98

    k_zero_deg<<<nodeBlocks, 256, 0, stream>>>(deg);
    k_count<<<edgeBlocks, 256, 0, stream>>>(dst, deg);
    k_scan_blocks<<<scanBlocks, 1024, 0, stream>>>(deg, row_off, blk);
    k_scan_tops<<<1, 64, 0, stream>>>(blk, blk_off, scanBlocks);
    k_finalize<<<nodeBlocks, 256, 0, stream>>>(deg, row_off, blk_off, cursor, dis);
    k_fill<<<edgeBlocks, 256, 0, stream>>>(src, dst, dis, cursor, csr);

    k_preproc<<<ncBlocks, 256, 0, stream>>>(x, W_pre, b_pre, W_fc1, b_fc1, W_fc2, b_fc2, ni, h);

    for (int l = 0; l < 6; l++) {
        k_transform<<<ncBlocks, 256, 0, stream>>>(h, W_gcn, g);
        k_gather<<<ncBlocks, 256, 0, stream>>>(g, csr, row_off, deg, dis, b_gcn, tbuf);
        k_dense<<<ncBlocks, 256, 0, stream>>>(ni, tbuf, W_dense, b_dense, h);
    }

    k_dense<<<ncBlocks, 256, 0, stream>>>(ni, h, W_f1, b_f1, g);   // g reused as u
    k_out<<<(NN * 2 + 255) / 256, 256, 0, stream>>>(g, W_f2, b_f2, (float*)d_out);
}

// Round 2
// 779.325 us; speedup vs baseline: 1.8373x; 1.8373x over previous
//
#include <hip/hip_runtime.h>
#include <math.h>

#define NN 100000
#define NE 3200000

// ---------------- CSR build ----------------

__global__ __launch_bounds__(256) void k_zero_deg(int* deg) {
    int i = blockIdx.x * blockDim.x + threadIdx.x;
    if (i < NN) deg[i] = 0;
}

__global__ __launch_bounds__(256) void k_count(const int* __restrict__ dst, int* __restrict__ deg) {
    int e = blockIdx.x * blockDim.x + threadIdx.x;
    if (e < NE) atomicAdd(&deg[dst[e]], 1);
}

__global__ __launch_bounds__(1024) void k_scan_blocks(const int* __restrict__ deg,
                                                      int* __restrict__ row_off,
                                                      int* __restrict__ blk) {
    __shared__ int s[1024];
    int i = blockIdx.x * 1024 + threadIdx.x;
    int v = (i < NN) ? deg[i] : 0;
    s[threadIdx.x] = v;
    __syncthreads();
    for (int off = 1; off < 1024; off <<= 1) {
        int t = (threadIdx.x >= off) ? s[threadIdx.x - off] : 0;
        __syncthreads();
        s[threadIdx.x] += t;
        __syncthreads();
    }
    if (i < NN) row_off[i] = s[threadIdx.x] - v;   // exclusive within block
    if (threadIdx.x == 1023) blk[blockIdx.x] = s[1023];
}

__global__ __launch_bounds__(64) void k_scan_tops(const int* __restrict__ blk,
                                                  int* __restrict__ blk_off, int nb) {
    if (threadIdx.x == 0 && blockIdx.x == 0) {
        int run = 0;
        for (int b = 0; b < nb; b++) { int t = blk[b]; blk_off[b] = run; run += t; }
    }
}

__global__ __launch_bounds__(256) void k_finalize(const int* __restrict__ deg,
                                                  int* __restrict__ row_off,
                                                  const int* __restrict__ blk_off,
                                                  int* __restrict__ cursor,
                                                  float* __restrict__ dis) {
    int i = blockIdx.x * blockDim.x + threadIdx.x;
    if (i < NN) {
        int r = row_off[i] + blk_off[i >> 10];
        row_off[i] = r;
        cursor[i]  = r;
        dis[i] = rsqrtf((float)deg[i] + 1.0f);  // deg over A+I
    }
}

__global__ __launch_bounds__(256) void k_fill(const int* __restrict__ src,
                                              const int* __restrict__ dst,
                                              const float* __restrict__ dis,
                                              int* __restrict__ cursor,
                                              int2* __restrict__ csr) {
    int e = blockIdx.x * blockDim.x + threadIdx.x;
    if (e < NE) {
        int s = src[e], d = dst[e];
        int pos = atomicAdd(&cursor[d], 1);
        float w = dis[s] * dis[d];
        csr[pos] = make_int2(s, __float_as_int(w));
    }
}

// ---------------- fused preproc (+ first GCN transform) ----------------
// Writes ni = relu(h0@W_fc1+b) and g0 = relu(h0@W_fc2+b) @ W_gcn.
// 8 lanes per node (q = 4-channel slice), 32 nodes per 256-thread block.
__global__ __launch_bounds__(256) void k_preproc(
        const float* __restrict__ x,
        const float* __restrict__ W_pre, const float* __restrict__ b_pre,
        const float* __restrict__ W_fc1, const float* __restrict__ b_fc1,
        const float* __restrict__ W_fc2, const float* __restrict__ b_fc2,
        const float* __restrict__ W_gcn,
        float* __restrict__ ni, float* __restrict__ g_out) {
    __shared__ __align__(16) float sWp[60];
    __shared__ __align__(16) float sbp[12];
    __shared__ __align__(16) float sW1[320];
    __shared__ __align__(16) float sb1[32];
    __shared__ __align__(16) float sW2[320];
    __shared__ __align__(16) float sb2[32];
    __shared__ __align__(16) float sWg[1024];
    __shared__ __align__(16) float s_h[32 * 36];
    int tid = threadIdx.x;
    if (tid < 60) sWp[tid] = W_pre[tid];
    if (tid >= 64 && tid < 74) sbp[tid - 64] = b_pre[tid - 64];
    for (int i = tid; i < 320; i += 256) { sW1[i] = W_fc1[i]; sW2[i] = W_fc2[i]; }
    if (tid >= 96 && tid < 128) sb1[tid - 96] = b_fc1[tid - 96];
    if (tid >= 128 && tid < 160) sb2[tid - 128] = b_fc2[tid - 128];
    for (int i = tid; i < 1024; i += 256) sWg[i] = W_gcn[i];
    __syncthreads();

    int ln = tid >> 3, q = tid & 7;
    int n = blockIdx.x * 32 + ln;

    float xv[6];
#pragma unroll
    for (int k = 0; k < 6; k++) xv[k] = x[n * 6 + k];
    float p[10];
#pragma unroll
    for (int j = 0; j < 10; j++) {
        float a = sbp[j];
#pragma unroll
        for (int k = 0; k < 6; k++) a = fmaf(xv[k], sWp[k * 10 + j], a);
        p[j] = 1.0f / (1.0f + expf(-a));
    }
    float4 a1 = ((const float4*)sb1)[q];
    float4 a2 = ((const float4*)sb2)[q];
#pragma unroll
    for (int k = 0; k < 10; k++) {
        float4 w1 = ((const float4*)sW1)[k * 8 + q];
        float4 w2 = ((const float4*)sW2)[k * 8 + q];
        a1.x = fmaf(p[k], w1.x, a1.x); a1.y = fmaf(p[k], w1.y, a1.y);
        a1.z = fmaf(p[k], w1.z, a1.z); a1.w = fmaf(p[k], w1.w, a1.w);
        a2.x = fmaf(p[k], w2.x, a2.x); a2.y = fmaf(p[k], w2.y, a2.y);
        a2.z = fmaf(p[k], w2.z, a2.z); a2.w = fmaf(p[k], w2.w, a2.w);
    }
    float4 niv, hv;
    niv.x = fmaxf(a1.x, 0.f); niv.y = fmaxf(a1.y, 0.f);
    niv.z = fmaxf(a1.z, 0.f); niv.w = fmaxf(a1.w, 0.f);
    hv.x = fmaxf(a2.x, 0.f); hv.y = fmaxf(a2.y, 0.f);
    hv.z = fmaxf(a2.z, 0.f); hv.w = fmaxf(a2.w, 0.f);
    ((float4*)ni)[n * 8 + q] = niv;
    *(float4*)&s_h[ln * 36 + 4 * q] = hv;
    __syncthreads();
    float4 o = make_float4(0.f, 0.f, 0.f, 0.f);
#pragma unroll
    for (int k = 0; k < 32; k++) {
        float v = s_h[ln * 36 + k];
        float4 wv = ((const float4*)sWg)[k * 8 + q];
        o.x = fmaf(v, wv.x, o.x); o.y = fmaf(v, wv.y, o.y);
        o.z = fmaf(v, wv.z, o.z); o.w = fmaf(v, wv.w, o.w);
    }
    ((float4*)g_out)[n * 8 + q] = o;
}

// ---------------- fused layer: gather + dense (+ transform | + head) ----------------
// 8 lanes per node (float4 channels), 32 nodes / 256-thread block, 3125 blocks.
template <bool LAST>
__global__ __launch_bounds__(256) void k_layer(
        const float* __restrict__ g_in,
        const int2* __restrict__ csr,
        const int* __restrict__ row_off,
        const int* __restrict__ deg,
        const float* __restrict__ dis,
        const float* __restrict__ ni,
        const float* __restrict__ W_dense, const float* __restrict__ b_dense,
        const float* __restrict__ b_gcn,
        const float* __restrict__ W2,          // LAST ? W_f1 : W_gcn
        const float* __restrict__ b_f1,        // LAST only
        const float* __restrict__ W_f2, const float* __restrict__ b_f2,  // LAST only
        float* __restrict__ out)               // LAST ? logits[NN*2] : g_out
{
    __shared__ __align__(16) float sWd[2048];
    __shared__ __align__(16) float sW2[LAST ? 2048 : 1024];
    __shared__ __align__(16) float sbd[32];
    __shared__ __align__(16) float sbg[32];
    __shared__ __align__(16) float sbf1[32];
    __shared__ __align__(16) float sWf2[64];
    __shared__ __align__(16) float sbf2[2];
    __shared__ __align__(16) float s_ni[32 * 36];
    __shared__ __align__(16) float s_t[32 * 36];

    int tid = threadIdx.x;
    for (int i = tid; i < 2048; i += 256) sWd[i] = W_dense[i];
    const int n2 = LAST ? 2048 : 1024;
    for (int i = tid; i < n2; i += 256) sW2[i] = W2[i];
    if (tid < 32) { sbd[tid] = b_dense[tid]; sbg[tid] = b_gcn[tid]; }
    if constexpr (LAST) {
        if (tid >= 64 && tid < 96) sbf1[tid - 64] = b_f1[tid - 64];
        if (tid >= 96 && tid < 160) sWf2[tid - 96] = W_f2[tid - 96];
        if (tid >= 160 && tid < 162) sbf2[tid - 160] = b_f2[tid - 160];
    }
    __syncthreads();

    int ln = tid >> 3, q = tid & 3 ? tid & 7 : tid & 7;  // q in [0,8)
    q = tid & 7;
    int n = blockIdx.x * 32 + ln;
    const float4* g4 = (const float4*)g_in;

    // ---- gather: agg over incoming edges + self-loop ----
    float4 acc;
    {
        float d = dis[n];
        float sn = d * d;
        float4 gs = g4[n * 8 + q];
        acc.x = gs.x * sn; acc.y = gs.y * sn; acc.z = gs.z * sn; acc.w = gs.w * sn;
    }
    int start = row_off[n], cnt = deg[n];
    int base = 0;
    for (; base + 8 <= cnt; base += 8) {
        int2 ev = csr[start + base + q];
#pragma unroll
        for (int j = 0; j < 8; j++) {
            int   s = __shfl(ev.x, j, 8);
            float w = __int_as_float(__shfl(ev.y, j, 8));
            float4 gv = g4[s * 8 + q];
            acc.x = fmaf(gv.x, w, acc.x); acc.y = fmaf(gv.y, w, acc.y);
            acc.z = fmaf(gv.z, w, acc.z); acc.w = fmaf(gv.w, w, acc.w);
        }
    }
    int rem = cnt - base;
    if (rem > 0) {
        int2 ev = make_int2(0, 0);
        if (q < rem) ev = csr[start + base + q];
        for (int j = 0; j < rem; j++) {
            int   s = __shfl(ev.x, j, 8);
            float w = __int_as_float(__shfl(ev.y, j, 8));
            float4 gv = g4[s * 8 + q];
            acc.x = fmaf(gv.x, w, acc.x); acc.y = fmaf(gv.y, w, acc.y);
            acc.z = fmaf(gv.z, w, acc.z); acc.w = fmaf(gv.w, w, acc.w);
        }
    }
    // t = relu(acc + b_gcn)
    float4 t;
    t.x = fmaxf(acc.x + sbg[4 * q + 0], 0.f);
    t.y = fmaxf(acc.y + sbg[4 * q + 1], 0.f);
    t.z = fmaxf(acc.z + sbg[4 * q + 2], 0.f);
    t.w = fmaxf(acc.w + sbg[4 * q + 3], 0.f);
    *(float4*)&s_t[ln * 36 + 4 * q] = t;
    float4 niv = ((const float4*)ni)[n * 8 + q];
    *(float4*)&s_ni[ln * 36 + 4 * q] = niv;
    __syncthreads();

    // ---- dense: h = relu(concat(ni, t) @ W_dense + b_dense) ----
    float4 a = ((const float4*)sbd)[q];
#pragma unroll
    for (int k = 0; k < 32; k++) {
        float v = s_ni[ln * 36 + k];
        float4 wv = ((const float4*)sWd)[k * 8 + q];
        a.x = fmaf(v, wv.x, a.x); a.y = fmaf(v, wv.y, a.y);
        a.z = fmaf(v, wv.z, a.z); a.w = fmaf(v, wv.w, a.w);
    }
#pragma unroll
    for (int k = 0; k < 32; k++) {
        float v = s_t[ln * 36 + k];
        float4 wv = ((const float4*)sWd)[(32 + k) * 8 + q];
        a.x = fmaf(v, wv.x, a.x); a.y = fmaf(v, wv.y, a.y);
        a.z = fmaf(v, wv.z, a.z); a.w = fmaf(v, wv.w, a.w);
    }
    float4 h;
    h.x = fmaxf(a.x, 0.f); h.y = fmaxf(a.y, 0.f);
    h.z = fmaxf(a.z, 0.f); h.w = fmaxf(a.w, 0.f);
    __syncthreads();                     // all reads of s_t done
    *(float4*)&s_t[ln * 36 + 4 * q] = h; // reuse s_t for h row
    __syncthreads();

    if constexpr (!LAST) {
        // ---- transform: g' = h @ W_gcn ----
        float4 o = make_float4(0.f, 0.f, 0.f, 0.f);
#pragma unroll
        for (int k = 0; k < 32; k++) {
            float v = s_t[ln * 36 + k];
            float4 wv = ((const float4*)sW2)[k * 8 + q];
            o.x = fmaf(v, wv.x, o.x); o.y = fmaf(v, wv.y, o.y);
            o.z = fmaf(v, wv.z, o.z); o.w = fmaf(v, wv.w, o.w);
        }
        ((float4*)out)[n * 8 + q] = o;
    } else {
        // ---- head: u = relu(concat(ni,h) @ W_f1 + b_f1); out = u @ W_f2 + b_f2 ----
        float4 a2 = ((const float4*)sbf1)[q];
#pragma unroll
        for (int k = 0; k < 32; k++) {
            float v = s_ni[ln * 36 + k];
            float4 wv = ((const float4*)sW2)[k * 8 + q];
            a2.x = fmaf(v, wv.x, a2.x); a2.y = fmaf(v, wv.y, a2.y);
            a2.z = fmaf(v, wv.z, a2.z); a2.w = fmaf(v, wv.w, a2.w);
        }
#pragma unroll
        for (int k = 0; k < 32; k++) {
            float v = s_t[ln * 36 + k];
            float4 wv = ((const float4*)sW2)[(32 + k) * 8 + q];
            a2.x = fmaf(v, wv.x, a2.x); a2.y = fmaf(v, wv.y, a2.y);
            a2.z = fmaf(v, wv.z, a2.z); a2.w = fmaf(v, wv.w, a2.w);
        }
        float4 u;
        u.x = fmaxf(a2.x, 0.f); u.y = fmaxf(a2.y, 0.f);
        u.z = fmaxf(a2.z, 0.f); u.w = fmaxf(a2.w, 0.f);
        float p0 = u.x * sWf2[(4 * q + 0) * 2 + 0] + u.y * sWf2[(4 * q + 1) * 2 + 0]
                 + u.z * sWf2[(4 * q + 2) * 2 + 0] + u.w * sWf2[(4 * q + 3) * 2 + 0];
        float p1 = u.x * sWf2[(4 * q + 0) * 2 + 1] + u.y * sWf2[(4 * q + 1) * 2 + 1]
                 + u.z * sWf2[(4 * q + 2) * 2 + 1] + u.w * sWf2[(4 * q + 3) * 2 + 1];
        p0 += __shfl_down(p0, 4, 8); p1 += __shfl_down(p1, 4, 8);
        p0 += __shfl_down(p0, 2, 8); p1 += __shfl_down(p1, 2, 8);
        p0 += __shfl_down(p0, 1, 8); p1 += __shfl_down(p1, 1, 8);
        if (q == 0) {
            out[n * 2 + 0] = p0 + sbf2[0];
            out[n * 2 + 1] = p1 + sbf2[1];
        }
    }
}

// ---------------- launch ----------------

extern "C" void kernel_launch(void* const* d_in, const int* in_sizes, int n_in,
                              void* d_out, int out_size, void* d_ws, size_t ws_size,
                              hipStream_t stream) {
    const float* x      = (const float*)d_in[0];
    const int*   ei     = (const int*)d_in[1];
    const float* W_pre  = (const float*)d_in[2];
    const float* b_pre  = (const float*)d_in[3];
    const float* W_fc1  = (const float*)d_in[4];
    const float* b_fc1  = (const float*)d_in[5];
    const float* W_fc2  = (const float*)d_in[6];
    const float* b_fc2  = (const float*)d_in[7];
    const float* W_gcn  = (const float*)d_in[8];
    const float* b_gcn  = (const float*)d_in[9];
    const float* W_dense= (const float*)d_in[10];
    const float* b_dense= (const float*)d_in[11];
    const float* W_f1   = (const float*)d_in[12];
    const float* b_f1   = (const float*)d_in[13];
    const float* W_f2   = (const float*)d_in[14];
    const float* b_f2   = (const float*)d_in[15];

    const int* src = ei;
    const int* dst = ei + NE;

    size_t off = 0;
    auto alloc = [&](size_t bytes) -> void* {
        off = (off + 255) & ~(size_t)255;
        void* p = (char*)d_ws + off;
        off += bytes;
        return p;
    };
    int*   deg     = (int*)  alloc(NN * sizeof(int));
    int*   row_off = (int*)  alloc(NN * sizeof(int));
    int*   cursor  = (int*)  alloc(NN * sizeof(int));
    int*   blk     = (int*)  alloc(128 * sizeof(int));
    int*   blk_off = (int*)  alloc(128 * sizeof(int));
    float* dis     = (float*)alloc(NN * sizeof(float));
    int2*  csr     = (int2*) alloc((size_t)NE * sizeof(int2));
    float* ni      = (float*)alloc((size_t)NN * 32 * sizeof(float));
    float* gA      = (float*)alloc((size_t)NN * 32 * sizeof(float));
    float* gB      = (float*)alloc((size_t)NN * 32 * sizeof(float));

    const int nodeBlocks = (NN + 255) / 256;    // 391
    const int edgeBlocks = (NE + 255) / 256;    // 12500
    const int scanBlocks = (NN + 1023) / 1024;  // 98
    const int fusedBlocks = NN / 32;            // 3125 (NN divisible by 32)

    k_zero_deg<<<nodeBlocks, 256, 0, stream>>>(deg);
    k_count<<<edgeBlocks, 256, 0, stream>>>(dst, deg);
    k_scan_blocks<<<scanBlocks, 1024, 0, stream>>>(deg, row_off, blk);
    k_scan_tops<<<1, 64, 0, stream>>>(blk, blk_off, scanBlocks);
    k_finalize<<<nodeBlocks, 256, 0, stream>>>(deg, row_off, blk_off, cursor, dis);
    k_fill<<<edgeBlocks, 256, 0, stream>>>(src, dst, dis, cursor, csr);

    k_preproc<<<fusedBlocks, 256, 0, stream>>>(x, W_pre, b_pre, W_fc1, b_fc1,
                                               W_fc2, b_fc2, W_gcn, ni, gA);

    float* gin = gA;
    float* gout = gB;
    for (int l = 0; l < 5; l++) {
        k_layer<false><<<fusedBlocks, 256, 0, stream>>>(
            gin, csr, row_off, deg, dis, ni, W_dense, b_dense, b_gcn,
            W_gcn, nullptr, nullptr, nullptr, gout);
        float* tmp = gin; gin = gout; gout = tmp;
    }
    k_layer<true><<<fusedBlocks, 256, 0, stream>>>(
        gin, csr, row_off, deg, dis, ni, W_dense, b_dense, b_gcn,
        W_f1, b_f1, W_f2, b_f2, (float*)d_out);
}

// Round 3
// 601.018 us; speedup vs baseline: 2.3824x; 1.2967x over previous
//
#include <hip/hip_runtime.h>
#include <math.h>

#define NN 100000
#define NE 3200000
#define NB 391          // dst-buckets of 256 nodes: 391*256 = 100096 >= NN
#define CAP 10240       // bin entries per bucket (max expected ~8550, fixed input)
#define EPB 8192        // edges per k_bin slab

// ---------------- binned CSR build ----------------

__global__ __launch_bounds__(512) void k_init_gcur(int* gcur) {
    int i = threadIdx.x;
    if (i < NB) gcur[i] = i * CAP;
}

// Pass 1: bin edges by dst>>8. Per-WG: LDS histogram -> reserve contiguous
// chunks via one global atomic per (WG,bucket) -> rescatter packed entries.
__global__ __launch_bounds__(256) void k_bin(const int* __restrict__ src,
                                             const int* __restrict__ dst,
                                             int* __restrict__ gcur,
                                             unsigned* __restrict__ bin) {
    __shared__ int hist[NB];
    __shared__ int base[NB];
    int tid = threadIdx.x;
    for (int i = tid; i < NB; i += 256) hist[i] = 0;
    __syncthreads();
    int e0 = blockIdx.x * EPB;
#pragma unroll 4
    for (int i = 0; i < EPB / 256; i++) {
        int e = e0 + i * 256 + tid;
        if (e < NE) atomicAdd(&hist[dst[e] >> 8], 1);
    }
    __syncthreads();
    for (int i = tid; i < NB; i += 256) {
        int c = hist[i];
        base[i] = (c > 0) ? atomicAdd(&gcur[i], c) : 0;
    }
    __syncthreads();
    for (int i = tid; i < NB; i += 256) hist[i] = 0;
    __syncthreads();
#pragma unroll 4
    for (int i = 0; i < EPB / 256; i++) {
        int e = e0 + i * 256 + tid;
        if (e < NE) {
            int d = dst[e];
            int b = d >> 8;
            int pos = base[b] + atomicAdd(&hist[b], 1);
            bin[pos] = ((unsigned)src[e] << 8) | (unsigned)(d & 255);
        }
    }
}

// Degrees via per-bucket LDS histogram (replaces 3.2M global atomics).
__global__ __launch_bounds__(256) void k_bucket_deg(const int* __restrict__ gcur,
                                                    const unsigned* __restrict__ bin,
                                                    int* __restrict__ deg) {
    __shared__ int dc[256];
    int b = blockIdx.x, tid = threadIdx.x;
    dc[tid] = 0;
    __syncthreads();
    int base = b * CAP, cnt = gcur[b] - base;
    for (int i = tid; i < cnt; i += 256) atomicAdd(&dc[bin[base + i] & 255], 1);
    __syncthreads();
    int node = b * 256 + tid;
    if (node < NN) deg[node] = dc[tid];
}

__global__ __launch_bounds__(1024) void k_scan_blocks(const int* __restrict__ deg,
                                                      int* __restrict__ row_off,
                                                      int* __restrict__ blk) {
    __shared__ int s[1024];
    int i = blockIdx.x * 1024 + threadIdx.x;
    int v = (i < NN) ? deg[i] : 0;
    s[threadIdx.x] = v;
    __syncthreads();
    for (int off = 1; off < 1024; off <<= 1) {
        int t = (threadIdx.x >= off) ? s[threadIdx.x - off] : 0;
        __syncthreads();
        s[threadIdx.x] += t;
        __syncthreads();
    }
    if (i < NN) row_off[i] = s[threadIdx.x] - v;   // exclusive within block
    if (threadIdx.x == 1023) blk[blockIdx.x] = s[1023];
}

__global__ __launch_bounds__(64) void k_scan_tops(const int* __restrict__ blk,
                                                  int* __restrict__ blk_off, int nb) {
    if (threadIdx.x == 0 && blockIdx.x == 0) {
        int run = 0;
        for (int b = 0; b < nb; b++) { int t = blk[b]; blk_off[b] = run; run += t; }
    }
}

__global__ __launch_bounds__(256) void k_finalize(const int* __restrict__ deg,
                                                  int* __restrict__ row_off,
                                                  const int* __restrict__ blk_off,
                                                  float* __restrict__ dis) {
    int i = blockIdx.x * blockDim.x + threadIdx.x;
    if (i < NN) {
        row_off[i] += blk_off[i >> 10];
        dis[i] = rsqrtf((float)deg[i] + 1.0f);  // deg over A+I
    }
}

// Pass 2: one WG per bucket; LDS cursors; all writes of a 64KB CSR region
// come from one CU -> lines fill completely in one L2 before writeback.
__global__ __launch_bounds__(256) void k_pass2(const int* __restrict__ gcur,
                                               const unsigned* __restrict__ bin,
                                               const int* __restrict__ row_off,
                                               const float* __restrict__ dis,
                                               int2* __restrict__ csr) {
    __shared__ int cur[256];
    __shared__ float sdis[256];
    int b = blockIdx.x, tid = threadIdx.x;
    int node = b * 256 + tid;
    cur[tid]  = (node < NN) ? row_off[node] : 0;
    sdis[tid] = (node < NN) ? dis[node] : 0.0f;
    __syncthreads();
    int base = b * CAP, cnt = gcur[b] - base;
    for (int i = tid; i < cnt; i += 256) {
        unsigned u = bin[base + i];
        int dl = u & 255;
        int s  = (int)(u >> 8);
        int pos = atomicAdd(&cur[dl], 1);
        float w = dis[s] * sdis[dl];
        csr[pos] = make_int2(s, __float_as_int(w));
    }
}

// ---------------- fused preproc (+ first GCN transform) ----------------
__global__ __launch_bounds__(256) void k_preproc(
        const float* __restrict__ x,
        const float* __restrict__ W_pre, const float* __restrict__ b_pre,
        const float* __restrict__ W_fc1, const float* __restrict__ b_fc1,
        const float* __restrict__ W_fc2, const float* __restrict__ b_fc2,
        const float* __restrict__ W_gcn,
        float* __restrict__ ni, float* __restrict__ g_out) {
    __shared__ __align__(16) float sWp[60];
    __shared__ __align__(16) float sbp[12];
    __shared__ __align__(16) float sW1[320];
    __shared__ __align__(16) float sb1[32];
    __shared__ __align__(16) float sW2[320];
    __shared__ __align__(16) float sb2[32];
    __shared__ __align__(16) float sWg[1024];
    __shared__ __align__(16) float s_h[32 * 36];
    int tid = threadIdx.x;
    if (tid < 60) sWp[tid] = W_pre[tid];
    if (tid >= 64 && tid < 74) sbp[tid - 64] = b_pre[tid - 64];
    for (int i = tid; i < 320; i += 256) { sW1[i] = W_fc1[i]; sW2[i] = W_fc2[i]; }
    if (tid >= 96 && tid < 128) sb1[tid - 96] = b_fc1[tid - 96];
    if (tid >= 128 && tid < 160) sb2[tid - 128] = b_fc2[tid - 128];
    for (int i = tid; i < 1024; i += 256) sWg[i] = W_gcn[i];
    __syncthreads();

    int ln = tid >> 3, q = tid & 7;
    int n = blockIdx.x * 32 + ln;

    float xv[6];
#pragma unroll
    for (int k = 0; k < 6; k++) xv[k] = x[n * 6 + k];
    float p[10];
#pragma unroll
    for (int j = 0; j < 10; j++) {
        float a = sbp[j];
#pragma unroll
        for (int k = 0; k < 6; k++) a = fmaf(xv[k], sWp[k * 10 + j], a);
        p[j] = 1.0f / (1.0f + expf(-a));
    }
    float4 a1 = ((const float4*)sb1)[q];
    float4 a2 = ((const float4*)sb2)[q];
#pragma unroll
    for (int k = 0; k < 10; k++) {
        float4 w1 = ((const float4*)sW1)[k * 8 + q];
        float4 w2 = ((const float4*)sW2)[k * 8 + q];
        a1.x = fmaf(p[k], w1.x, a1.x); a1.y = fmaf(p[k], w1.y, a1.y);
        a1.z = fmaf(p[k], w1.z, a1.z); a1.w = fmaf(p[k], w1.w, a1.w);
        a2.x = fmaf(p[k], w2.x, a2.x); a2.y = fmaf(p[k], w2.y, a2.y);
        a2.z = fmaf(p[k], w2.z, a2.z); a2.w = fmaf(p[k], w2.w, a2.w);
    }
    float4 niv, hv;
    niv.x = fmaxf(a1.x, 0.f); niv.y = fmaxf(a1.y, 0.f);
    niv.z = fmaxf(a1.z, 0.f); niv.w = fmaxf(a1.w, 0.f);
    hv.x = fmaxf(a2.x, 0.f); hv.y = fmaxf(a2.y, 0.f);
    hv.z = fmaxf(a2.z, 0.f); hv.w = fmaxf(a2.w, 0.f);
    ((float4*)ni)[n * 8 + q] = niv;
    *(float4*)&s_h[ln * 36 + 4 * q] = hv;
    __syncthreads();
    float4 o = make_float4(0.f, 0.f, 0.f, 0.f);
#pragma unroll
    for (int k = 0; k < 32; k++) {
        float v = s_h[ln * 36 + k];
        float4 wv = ((const float4*)sWg)[k * 8 + q];
        o.x = fmaf(v, wv.x, o.x); o.y = fmaf(v, wv.y, o.y);
        o.z = fmaf(v, wv.z, o.z); o.w = fmaf(v, wv.w, o.w);
    }
    ((float4*)g_out)[n * 8 + q] = o;
}

// ---------------- fused layer: gather + dense (+ transform | + head) ----------------
template <bool LAST>
__global__ __launch_bounds__(256) void k_layer(
        const float* __restrict__ g_in,
        const int2* __restrict__ csr,
        const int* __restrict__ row_off,
        const int* __restrict__ deg,
        const float* __restrict__ dis,
        const float* __restrict__ ni,
        const float* __restrict__ W_dense, const float* __restrict__ b_dense,
        const float* __restrict__ b_gcn,
        const float* __restrict__ W2,          // LAST ? W_f1 : W_gcn
        const float* __restrict__ b_f1,        // LAST only
        const float* __restrict__ W_f2, const float* __restrict__ b_f2,  // LAST only
        float* __restrict__ out)               // LAST ? logits[NN*2] : g_out
{
    __shared__ __align__(16) float sWd[2048];
    __shared__ __align__(16) float sW2[LAST ? 2048 : 1024];
    __shared__ __align__(16) float sbd[32];
    __shared__ __align__(16) float sbg[32];
    __shared__ __align__(16) float sbf1[32];
    __shared__ __align__(16) float sWf2[64];
    __shared__ __align__(16) float sbf2[2];
    __shared__ __align__(16) float s_ni[32 * 36];
    __shared__ __align__(16) float s_t[32 * 36];

    int tid = threadIdx.x;
    for (int i = tid; i < 2048; i += 256) sWd[i] = W_dense[i];
    const int n2 = LAST ? 2048 : 1024;
    for (int i = tid; i < n2; i += 256) sW2[i] = W2[i];
    if (tid < 32) { sbd[tid] = b_dense[tid]; sbg[tid] = b_gcn[tid]; }
    if constexpr (LAST) {
        if (tid >= 64 && tid < 96) sbf1[tid - 64] = b_f1[tid - 64];
        if (tid >= 96 && tid < 160) sWf2[tid - 96] = W_f2[tid - 96];
        if (tid >= 160 && tid < 162) sbf2[tid - 160] = b_f2[tid - 160];
    }
    __syncthreads();

    int ln = tid >> 3, q = tid & 7;
    int n = blockIdx.x * 32 + ln;
    const float4* g4 = (const float4*)g_in;

    // ---- gather ----
    float4 acc;
    {
        float d = dis[n];
        float sn = d * d;
        float4 gs = g4[n * 8 + q];
        acc.x = gs.x * sn; acc.y = gs.y * sn; acc.z = gs.z * sn; acc.w = gs.w * sn;
    }
    int start = row_off[n], cnt = deg[n];
    int base = 0;
    for (; base + 8 <= cnt; base += 8) {
        int2 ev = csr[start + base + q];
#pragma unroll
        for (int j = 0; j < 8; j++) {
            int   s = __shfl(ev.x, j, 8);
            float w = __int_as_float(__shfl(ev.y, j, 8));
            float4 gv = g4[s * 8 + q];
            acc.x = fmaf(gv.x, w, acc.x); acc.y = fmaf(gv.y, w, acc.y);
            acc.z = fmaf(gv.z, w, acc.z); acc.w = fmaf(gv.w, w, acc.w);
        }
    }
    int rem = cnt - base;
    if (rem > 0) {
        int2 ev = make_int2(0, 0);
        if (q < rem) ev = csr[start + base + q];
        for (int j = 0; j < rem; j++) {
            int   s = __shfl(ev.x, j, 8);
            float w = __int_as_float(__shfl(ev.y, j, 8));
            float4 gv = g4[s * 8 + q];
            acc.x = fmaf(gv.x, w, acc.x); acc.y = fmaf(gv.y, w, acc.y);
            acc.z = fmaf(gv.z, w, acc.z); acc.w = fmaf(gv.w, w, acc.w);
        }
    }
    float4 t;
    t.x = fmaxf(acc.x + sbg[4 * q + 0], 0.f);
    t.y = fmaxf(acc.y + sbg[4 * q + 1], 0.f);
    t.z = fmaxf(acc.z + sbg[4 * q + 2], 0.f);
    t.w = fmaxf(acc.w + sbg[4 * q + 3], 0.f);
    *(float4*)&s_t[ln * 36 + 4 * q] = t;
    float4 niv = ((const float4*)ni)[n * 8 + q];
    *(float4*)&s_ni[ln * 36 + 4 * q] = niv;
    __syncthreads();

    // ---- dense ----
    float4 a = ((const float4*)sbd)[q];
#pragma unroll
    for (int k = 0; k < 32; k++) {
        float v = s_ni[ln * 36 + k];
        float4 wv = ((const float4*)sWd)[k * 8 + q];
        a.x = fmaf(v, wv.x, a.x); a.y = fmaf(v, wv.y, a.y);
        a.z = fmaf(v, wv.z, a.z); a.w = fmaf(v, wv.w, a.w);
    }
#pragma unroll
    for (int k = 0; k < 32; k++) {
        float v = s_t[ln * 36 + k];
        float4 wv = ((const float4*)sWd)[(32 + k) * 8 + q];
        a.x = fmaf(v, wv.x, a.x); a.y = fmaf(v, wv.y, a.y);
        a.z = fmaf(v, wv.z, a.z); a.w = fmaf(v, wv.w, a.w);
    }
    float4 h;
    h.x = fmaxf(a.x, 0.f); h.y = fmaxf(a.y, 0.f);
    h.z = fmaxf(a.z, 0.f); h.w = fmaxf(a.w, 0.f);
    __syncthreads();
    *(float4*)&s_t[ln * 36 + 4 * q] = h;
    __syncthreads();

    if constexpr (!LAST) {
        float4 o = make_float4(0.f, 0.f, 0.f, 0.f);
#pragma unroll
        for (int k = 0; k < 32; k++) {
            float v = s_t[ln * 36 + k];
            float4 wv = ((const float4*)sW2)[k * 8 + q];
            o.x = fmaf(v, wv.x, o.x); o.y = fmaf(v, wv.y, o.y);
            o.z = fmaf(v, wv.z, o.z); o.w = fmaf(v, wv.w, o.w);
        }
        ((float4*)out)[n * 8 + q] = o;
    } else {
        float4 a2 = ((const float4*)sbf1)[q];
#pragma unroll
        for (int k = 0; k < 32; k++) {
            float v = s_ni[ln * 36 + k];
            float4 wv = ((const float4*)sW2)[k * 8 + q];
            a2.x = fmaf(v, wv.x, a2.x); a2.y = fmaf(v, wv.y, a2.y);
            a2.z = fmaf(v, wv.z, a2.z); a2.w = fmaf(v, wv.w, a2.w);
        }
#pragma unroll
        for (int k = 0; k < 32; k++) {
            float v = s_t[ln * 36 + k];
            float4 wv = ((const float4*)sW2)[(32 + k) * 8 + q];
            a2.x = fmaf(v, wv.x, a2.x); a2.y = fmaf(v, wv.y, a2.y);
            a2.z = fmaf(v, wv.z, a2.z); a2.w = fmaf(v, wv.w, a2.w);
        }
        float4 u;
        u.x = fmaxf(a2.x, 0.f); u.y = fmaxf(a2.y, 0.f);
        u.z = fmaxf(a2.z, 0.f); u.w = fmaxf(a2.w, 0.f);
        float p0 = u.x * sWf2[(4 * q + 0) * 2 + 0] + u.y * sWf2[(4 * q + 1) * 2 + 0]
                 + u.z * sWf2[(4 * q + 2) * 2 + 0] + u.w * sWf2[(4 * q + 3) * 2 + 0];
        float p1 = u.x * sWf2[(4 * q + 0) * 2 + 1] + u.y * sWf2[(4 * q + 1) * 2 + 1]
                 + u.z * sWf2[(4 * q + 2) * 2 + 1] + u.w * sWf2[(4 * q + 3) * 2 + 1];
        p0 += __shfl_down(p0, 4, 8); p1 += __shfl_down(p1, 4, 8);
        p0 += __shfl_down(p0, 2, 8); p1 += __shfl_down(p1, 2, 8);
        p0 += __shfl_down(p0, 1, 8); p1 += __shfl_down(p1, 1, 8);
        if (q == 0) {
            out[n * 2 + 0] = p0 + sbf2[0];
            out[n * 2 + 1] = p1 + sbf2[1];
        }
    }
}

// ---------------- launch ----------------

extern "C" void kernel_launch(void* const* d_in, const int* in_sizes, int n_in,
                              void* d_out, int out_size, void* d_ws, size_t ws_size,
                              hipStream_t stream) {
    const float* x      = (const float*)d_in[0];
    const int*   ei     = (const int*)d_in[1];
    const float* W_pre  = (const float*)d_in[2];
    const float* b_pre  = (const float*)d_in[3];
    const float* W_fc1  = (const float*)d_in[4];
    const float* b_fc1  = (const float*)d_in[5];
    const float* W_fc2  = (const float*)d_in[6];
    const float* b_fc2  = (const float*)d_in[7];
    const float* W_gcn  = (const float*)d_in[8];
    const float* b_gcn  = (const float*)d_in[9];
    const float* W_dense= (const float*)d_in[10];
    const float* b_dense= (const float*)d_in[11];
    const float* W_f1   = (const float*)d_in[12];
    const float* b_f1   = (const float*)d_in[13];
    const float* W_f2   = (const float*)d_in[14];
    const float* b_f2   = (const float*)d_in[15];

    const int* src = ei;
    const int* dst = ei + NE;

    size_t off = 0;
    auto alloc = [&](size_t bytes) -> void* {
        off = (off + 255) & ~(size_t)255;
        void* p = (char*)d_ws + off;
        off += bytes;
        return p;
    };
    int*   deg     = (int*)  alloc(NN * sizeof(int));
    int*   row_off = (int*)  alloc(NN * sizeof(int));
    int*   blk     = (int*)  alloc(128 * sizeof(int));
    int*   blk_off = (int*)  alloc(128 * sizeof(int));
    float* dis     = (float*)alloc(NN * sizeof(float));
    int*   gcur    = (int*)  alloc(NB * sizeof(int));
    int2*  csr     = (int2*) alloc((size_t)NE * sizeof(int2));
    // bin (16 MB) overlays gA+gB (25.6 MB): bin dead before k_preproc writes gA.
    char*  Ureg    = (char*) alloc(2 * (size_t)NN * 32 * sizeof(float));
    float* ni      = (float*)alloc((size_t)NN * 32 * sizeof(float));
    unsigned* bin  = (unsigned*)Ureg;
    float* gA      = (float*)Ureg;
    float* gB      = (float*)(Ureg + (size_t)NN * 32 * sizeof(float));

    const int scanBlocks  = (NN + 1023) / 1024;  // 98
    const int nodeBlocks  = (NN + 255) / 256;    // 391
    const int binBlocks   = (NE + EPB - 1) / EPB; // 391
    const int fusedBlocks = NN / 32;             // 3125

    k_init_gcur<<<1, 512, 0, stream>>>(gcur);
    k_bin<<<binBlocks, 256, 0, stream>>>(src, dst, gcur, bin);
    k_bucket_deg<<<NB, 256, 0, stream>>>(gcur, bin, deg);
    k_scan_blocks<<<scanBlocks, 1024, 0, stream>>>(deg, row_off, blk);
    k_scan_tops<<<1, 64, 0, stream>>>(blk, blk_off, scanBlocks);
    k_finalize<<<nodeBlocks, 256, 0, stream>>>(deg, row_off, blk_off, dis);
    k_pass2<<<NB, 256, 0, stream>>>(gcur, bin, row_off, dis, csr);

    k_preproc<<<fusedBlocks, 256, 0, stream>>>(x, W_pre, b_pre, W_fc1, b_fc1,
                                               W_fc2, b_fc2, W_gcn, ni, gA);

    float* gin = gA;
    float* gout = gB;
    for (int l = 0; l < 5; l++) {
        k_layer<false><<<fusedBlocks, 256, 0, stream>>>(
            gin, csr, row_off, deg, dis, ni, W_dense, b_dense, b_gcn,
            W_gcn, nullptr, nullptr, nullptr, gout);
        float* tmp = gin; gin = gout; gout = tmp;
    }
    k_layer<true><<<fusedBlocks, 256, 0, stream>>>(
        gin, csr, row_off, deg, dis, ni, W_dense, b_dense, b_gcn,
        W_f1, b_f1, W_f2, b_f2, (float*)d_out);
}

// Round 4
// 492.202 us; speedup vs baseline: 2.9091x; 1.2211x over previous
//
#include <hip/hip_runtime.h>
#include <math.h>

#define NN 100000
#define NE 3200000
#define NB 391          // dst-buckets of 256 nodes: 391*256 = 100096 >= NN
#define CAP 10240       // bin entries per bucket (max expected ~8550, fixed input)
#define EPB 4096        // edges per k_bin slab

typedef _Float16 half4 __attribute__((ext_vector_type(4)));

// ---------------- binned CSR build ----------------

__global__ __launch_bounds__(512) void k_init_gcur(int* gcur) {
    int i = threadIdx.x;
    if (i < NB) gcur[i] = i * CAP;
}

// Pass 1: bin edges by dst>>8. dst cached in regs (read once).
__global__ __launch_bounds__(256) void k_bin(const int* __restrict__ src,
                                             const int* __restrict__ dst,
                                             int* __restrict__ gcur,
                                             unsigned* __restrict__ bin) {
    __shared__ int hist[NB];
    __shared__ int base[NB];
    int tid = threadIdx.x;
    for (int i = tid; i < NB; i += 256) hist[i] = 0;
    __syncthreads();
    int e0 = blockIdx.x * EPB;
    int dcache[EPB / 256];
#pragma unroll
    for (int i = 0; i < EPB / 256; i++) {
        int e = e0 + i * 256 + tid;
        dcache[i] = (e < NE) ? dst[e] : -1;
        if (dcache[i] >= 0) atomicAdd(&hist[dcache[i] >> 8], 1);
    }
    __syncthreads();
    for (int i = tid; i < NB; i += 256) {
        int c = hist[i];
        base[i] = (c > 0) ? atomicAdd(&gcur[i], c) : 0;
    }
    __syncthreads();
    for (int i = tid; i < NB; i += 256) hist[i] = 0;
    __syncthreads();
#pragma unroll
    for (int i = 0; i < EPB / 256; i++) {
        int e = e0 + i * 256 + tid;
        int d = dcache[i];
        if (d >= 0) {
            int b = d >> 8;
            int pos = base[b] + atomicAdd(&hist[b], 1);
            bin[pos] = ((unsigned)src[e] << 8) | (unsigned)(d & 255);
        }
    }
}

__global__ __launch_bounds__(1024) void k_bucket_deg(const int* __restrict__ gcur,
                                                     const unsigned* __restrict__ bin,
                                                     int* __restrict__ deg) {
    __shared__ int dc[256];
    int b = blockIdx.x, tid = threadIdx.x;
    if (tid < 256) dc[tid] = 0;
    __syncthreads();
    int base = b * CAP, cnt = gcur[b] - base;
    for (int i = tid; i < cnt; i += 1024) atomicAdd(&dc[bin[base + i] & 255], 1);
    __syncthreads();
    int node = b * 256 + tid;
    if (tid < 256 && node < NN) deg[node] = dc[tid];
}

__global__ __launch_bounds__(1024) void k_scan_blocks(const int* __restrict__ deg,
                                                      int* __restrict__ row_off,
                                                      int* __restrict__ blk) {
    __shared__ int s[1024];
    int i = blockIdx.x * 1024 + threadIdx.x;
    int v = (i < NN) ? deg[i] : 0;
    s[threadIdx.x] = v;
    __syncthreads();
    for (int off = 1; off < 1024; off <<= 1) {
        int t = (threadIdx.x >= off) ? s[threadIdx.x - off] : 0;
        __syncthreads();
        s[threadIdx.x] += t;
        __syncthreads();
    }
    if (i < NN) row_off[i] = s[threadIdx.x] - v;
    if (threadIdx.x == 1023) blk[blockIdx.x] = s[1023];
}

__global__ __launch_bounds__(64) void k_scan_tops(const int* __restrict__ blk,
                                                  int* __restrict__ blk_off, int nb) {
    if (threadIdx.x == 0 && blockIdx.x == 0) {
        int run = 0;
        for (int b = 0; b < nb; b++) { int t = blk[b]; blk_off[b] = run; run += t; }
    }
}

__global__ __launch_bounds__(256) void k_finalize(const int* __restrict__ deg,
                                                  int* __restrict__ row_off,
                                                  const int* __restrict__ blk_off,
                                                  float* __restrict__ dis) {
    int i = blockIdx.x * blockDim.x + threadIdx.x;
    if (i < NN) {
        row_off[i] += blk_off[i >> 10];
        dis[i] = rsqrtf((float)deg[i] + 1.0f);
    }
}

__global__ __launch_bounds__(1024) void k_pass2(const int* __restrict__ gcur,
                                                const unsigned* __restrict__ bin,
                                                const int* __restrict__ row_off,
                                                const float* __restrict__ dis,
                                                int2* __restrict__ csr) {
    __shared__ int cur[256];
    __shared__ float sdis[256];
    int b = blockIdx.x, tid = threadIdx.x;
    int node = b * 256 + tid;
    if (tid < 256) {
        cur[tid]  = (node < NN) ? row_off[node] : 0;
        sdis[tid] = (node < NN) ? dis[node] : 0.0f;
    }
    __syncthreads();
    int base = b * CAP, cnt = gcur[b] - base;
    for (int i = tid; i < cnt; i += 1024) {
        unsigned u = bin[base + i];
        int dl = u & 255;
        int s  = (int)(u >> 8);
        int pos = atomicAdd(&cur[dl], 1);
        float w = dis[s] * sdis[dl];
        csr[pos] = make_int2(s, __float_as_int(w));
    }
}

// ---------------- fused preproc (+ first GCN transform) ----------------
// ni and g_out now fp16 (half4 per lane).
__global__ __launch_bounds__(256) void k_preproc(
        const float* __restrict__ x,
        const float* __restrict__ W_pre, const float* __restrict__ b_pre,
        const float* __restrict__ W_fc1, const float* __restrict__ b_fc1,
        const float* __restrict__ W_fc2, const float* __restrict__ b_fc2,
        const float* __restrict__ W_gcn,
        half4* __restrict__ ni, half4* __restrict__ g_out) {
    __shared__ __align__(16) float sWp[60];
    __shared__ __align__(16) float sbp[12];
    __shared__ __align__(16) float sW1[320];
    __shared__ __align__(16) float sb1[32];
    __shared__ __align__(16) float sW2[320];
    __shared__ __align__(16) float sb2[32];
    __shared__ __align__(16) float sWg[1024];
    __shared__ __align__(16) float s_h[32 * 36];
    int tid = threadIdx.x;
    if (tid < 60) sWp[tid] = W_pre[tid];
    if (tid >= 64 && tid < 74) sbp[tid - 64] = b_pre[tid - 64];
    for (int i = tid; i < 320; i += 256) { sW1[i] = W_fc1[i]; sW2[i] = W_fc2[i]; }
    if (tid >= 96 && tid < 128) sb1[tid - 96] = b_fc1[tid - 96];
    if (tid >= 128 && tid < 160) sb2[tid - 128] = b_fc2[tid - 128];
    for (int i = tid; i < 1024; i += 256) sWg[i] = W_gcn[i];
    __syncthreads();

    int ln = tid >> 3, q = tid & 7;
    int n = blockIdx.x * 32 + ln;

    float xv[6];
#pragma unroll
    for (int k = 0; k < 6; k++) xv[k] = x[n * 6 + k];
    float p[10];
#pragma unroll
    for (int j = 0; j < 10; j++) {
        float a = sbp[j];
#pragma unroll
        for (int k = 0; k < 6; k++) a = fmaf(xv[k], sWp[k * 10 + j], a);
        p[j] = 1.0f / (1.0f + expf(-a));
    }
    float4 a1 = ((const float4*)sb1)[q];
    float4 a2 = ((const float4*)sb2)[q];
#pragma unroll
    for (int k = 0; k < 10; k++) {
        float4 w1 = ((const float4*)sW1)[k * 8 + q];
        float4 w2 = ((const float4*)sW2)[k * 8 + q];
        a1.x = fmaf(p[k], w1.x, a1.x); a1.y = fmaf(p[k], w1.y, a1.y);
        a1.z = fmaf(p[k], w1.z, a1.z); a1.w = fmaf(p[k], w1.w, a1.w);
        a2.x = fmaf(p[k], w2.x, a2.x); a2.y = fmaf(p[k], w2.y, a2.y);
        a2.z = fmaf(p[k], w2.z, a2.z); a2.w = fmaf(p[k], w2.w, a2.w);
    }
    half4 niv;
    niv.x = (_Float16)fmaxf(a1.x, 0.f); niv.y = (_Float16)fmaxf(a1.y, 0.f);
    niv.z = (_Float16)fmaxf(a1.z, 0.f); niv.w = (_Float16)fmaxf(a1.w, 0.f);
    ni[n * 8 + q] = niv;
    float4 hv;
    hv.x = fmaxf(a2.x, 0.f); hv.y = fmaxf(a2.y, 0.f);
    hv.z = fmaxf(a2.z, 0.f); hv.w = fmaxf(a2.w, 0.f);
    *(float4*)&s_h[ln * 36 + 4 * q] = hv;
    __syncthreads();
    float4 o = make_float4(0.f, 0.f, 0.f, 0.f);
#pragma unroll
    for (int k = 0; k < 32; k++) {
        float v = s_h[ln * 36 + k];
        float4 wv = ((const float4*)sWg)[k * 8 + q];
        o.x = fmaf(v, wv.x, o.x); o.y = fmaf(v, wv.y, o.y);
        o.z = fmaf(v, wv.z, o.z); o.w = fmaf(v, wv.w, o.w);
    }
    half4 oh;
    oh.x = (_Float16)o.x; oh.y = (_Float16)o.y;
    oh.z = (_Float16)o.z; oh.w = (_Float16)o.w;
    g_out[n * 8 + q] = oh;
}

// ---------------- fused layer ----------------
template <bool LAST>
__global__ __launch_bounds__(256) void k_layer(
        const half4* __restrict__ g_in,
        const int2* __restrict__ csr,
        const int* __restrict__ row_off,
        const int* __restrict__ deg,
        const float* __restrict__ dis,
        const half4* __restrict__ ni,
        const float* __restrict__ W_dense, const float* __restrict__ b_dense,
        const float* __restrict__ b_gcn,
        const float* __restrict__ W2,          // LAST ? W_f1 : W_gcn
        const float* __restrict__ b_f1,
        const float* __restrict__ W_f2, const float* __restrict__ b_f2,
        void* __restrict__ out)                // LAST ? float logits : half4 g_out
{
    __shared__ __align__(16) float sWd[2048];
    __shared__ __align__(16) float sW2[LAST ? 2048 : 1024];
    __shared__ __align__(16) float sbd[32];
    __shared__ __align__(16) float sbg[32];
    __shared__ __align__(16) float sbf1[32];
    __shared__ __align__(16) float sWf2[64];
    __shared__ __align__(16) float sbf2[2];
    __shared__ __align__(16) float s_ni[32 * 36];
    __shared__ __align__(16) float s_t[32 * 36];

    int tid = threadIdx.x;
    for (int i = tid; i < 2048; i += 256) sWd[i] = W_dense[i];
    const int n2 = LAST ? 2048 : 1024;
    for (int i = tid; i < n2; i += 256) sW2[i] = W2[i];
    if (tid < 32) { sbd[tid] = b_dense[tid]; sbg[tid] = b_gcn[tid]; }
    if constexpr (LAST) {
        if (tid >= 64 && tid < 96) sbf1[tid - 64] = b_f1[tid - 64];
        if (tid >= 96 && tid < 160) sWf2[tid - 96] = W_f2[tid - 96];
        if (tid >= 160 && tid < 162) sbf2[tid - 160] = b_f2[tid - 160];
    }
    __syncthreads();

    int ln = tid >> 3, q = tid & 7;
    int n = blockIdx.x * 32 + ln;

    // ---- gather (fp16 g rows, 2 ev-batches in flight, branchless tail) ----
    float4 acc;
    {
        float d = dis[n];
        float sn = d * d;
        half4 gs = g_in[n * 8 + q];
        acc.x = (float)gs.x * sn; acc.y = (float)gs.y * sn;
        acc.z = (float)gs.z * sn; acc.w = (float)gs.w * sn;
    }
    int start = row_off[n], cnt = deg[n];
    int nbat = (cnt + 7) >> 3;
    const long long* csr8 = (const long long*)csr;
    for (int b = 0; b < nbat; b += 2) {
        int i0 = b * 8 + q, i1 = i0 + 8;
        long long e0 = 0, e1 = 0;
        if (i0 < cnt) e0 = __builtin_nontemporal_load(csr8 + start + i0);
        if (i1 < cnt) e1 = __builtin_nontemporal_load(csr8 + start + i1);
#pragma unroll
        for (int j = 0; j < 8; j++) {
            int   s = __shfl((int)e0, j, 8);
            float w = __int_as_float(__shfl((int)((unsigned long long)e0 >> 32), j, 8));
            half4 gv = g_in[s * 8 + q];
            acc.x = fmaf((float)gv.x, w, acc.x); acc.y = fmaf((float)gv.y, w, acc.y);
            acc.z = fmaf((float)gv.z, w, acc.z); acc.w = fmaf((float)gv.w, w, acc.w);
        }
        if (b + 1 < nbat) {
#pragma unroll
            for (int j = 0; j < 8; j++) {
                int   s = __shfl((int)e1, j, 8);
                float w = __int_as_float(__shfl((int)((unsigned long long)e1 >> 32), j, 8));
                half4 gv = g_in[s * 8 + q];
                acc.x = fmaf((float)gv.x, w, acc.x); acc.y = fmaf((float)gv.y, w, acc.y);
                acc.z = fmaf((float)gv.z, w, acc.z); acc.w = fmaf((float)gv.w, w, acc.w);
            }
        }
    }
    float4 t;
    t.x = fmaxf(acc.x + sbg[4 * q + 0], 0.f);
    t.y = fmaxf(acc.y + sbg[4 * q + 1], 0.f);
    t.z = fmaxf(acc.z + sbg[4 * q + 2], 0.f);
    t.w = fmaxf(acc.w + sbg[4 * q + 3], 0.f);
    *(float4*)&s_t[ln * 36 + 4 * q] = t;
    {
        half4 nv = ni[n * 8 + q];
        float4 nf = make_float4((float)nv.x, (float)nv.y, (float)nv.z, (float)nv.w);
        *(float4*)&s_ni[ln * 36 + 4 * q] = nf;
    }
    __syncthreads();

    // ---- dense ----
    float4 a = ((const float4*)sbd)[q];
#pragma unroll
    for (int k = 0; k < 32; k++) {
        float v = s_ni[ln * 36 + k];
        float4 wv = ((const float4*)sWd)[k * 8 + q];
        a.x = fmaf(v, wv.x, a.x); a.y = fmaf(v, wv.y, a.y);
        a.z = fmaf(v, wv.z, a.z); a.w = fmaf(v, wv.w, a.w);
    }
#pragma unroll
    for (int k = 0; k < 32; k++) {
        float v = s_t[ln * 36 + k];
        float4 wv = ((const float4*)sWd)[(32 + k) * 8 + q];
        a.x = fmaf(v, wv.x, a.x); a.y = fmaf(v, wv.y, a.y);
        a.z = fmaf(v, wv.z, a.z); a.w = fmaf(v, wv.w, a.w);
    }
    float4 h;
    h.x = fmaxf(a.x, 0.f); h.y = fmaxf(a.y, 0.f);
    h.z = fmaxf(a.z, 0.f); h.w = fmaxf(a.w, 0.f);
    __syncthreads();
    *(float4*)&s_t[ln * 36 + 4 * q] = h;
    __syncthreads();

    if constexpr (!LAST) {
        float4 o = make_float4(0.f, 0.f, 0.f, 0.f);
#pragma unroll
        for (int k = 0; k < 32; k++) {
            float v = s_t[ln * 36 + k];
            float4 wv = ((const float4*)sW2)[k * 8 + q];
            o.x = fmaf(v, wv.x, o.x); o.y = fmaf(v, wv.y, o.y);
            o.z = fmaf(v, wv.z, o.z); o.w = fmaf(v, wv.w, o.w);
        }
        half4 oh;
        oh.x = (_Float16)o.x; oh.y = (_Float16)o.y;
        oh.z = (_Float16)o.z; oh.w = (_Float16)o.w;
        ((half4*)out)[n * 8 + q] = oh;
    } else {
        float4 a2 = ((const float4*)sbf1)[q];
#pragma unroll
        for (int k = 0; k < 32; k++) {
            float v = s_ni[ln * 36 + k];
            float4 wv = ((const float4*)sW2)[k * 8 + q];
            a2.x = fmaf(v, wv.x, a2.x); a2.y = fmaf(v, wv.y, a2.y);
            a2.z = fmaf(v, wv.z, a2.z); a2.w = fmaf(v, wv.w, a2.w);
        }
#pragma unroll
        for (int k = 0; k < 32; k++) {
            float v = s_t[ln * 36 + k];
            float4 wv = ((const float4*)sW2)[(32 + k) * 8 + q];
            a2.x = fmaf(v, wv.x, a2.x); a2.y = fmaf(v, wv.y, a2.y);
            a2.z = fmaf(v, wv.z, a2.z); a2.w = fmaf(v, wv.w, a2.w);
        }
        float4 u;
        u.x = fmaxf(a2.x, 0.f); u.y = fmaxf(a2.y, 0.f);
        u.z = fmaxf(a2.z, 0.f); u.w = fmaxf(a2.w, 0.f);
        float p0 = u.x * sWf2[(4 * q + 0) * 2 + 0] + u.y * sWf2[(4 * q + 1) * 2 + 0]
                 + u.z * sWf2[(4 * q + 2) * 2 + 0] + u.w * sWf2[(4 * q + 3) * 2 + 0];
        float p1 = u.x * sWf2[(4 * q + 0) * 2 + 1] + u.y * sWf2[(4 * q + 1) * 2 + 1]
                 + u.z * sWf2[(4 * q + 2) * 2 + 1] + u.w * sWf2[(4 * q + 3) * 2 + 1];
        p0 += __shfl_down(p0, 4, 8); p1 += __shfl_down(p1, 4, 8);
        p0 += __shfl_down(p0, 2, 8); p1 += __shfl_down(p1, 2, 8);
        p0 += __shfl_down(p0, 1, 8); p1 += __shfl_down(p1, 1, 8);
        if (q == 0) {
            ((float*)out)[n * 2 + 0] = p0 + sbf2[0];
            ((float*)out)[n * 2 + 1] = p1 + sbf2[1];
        }
    }
}

// ---------------- launch ----------------

extern "C" void kernel_launch(void* const* d_in, const int* in_sizes, int n_in,
                              void* d_out, int out_size, void* d_ws, size_t ws_size,
                              hipStream_t stream) {
    const float* x      = (const float*)d_in[0];
    const int*   ei     = (const int*)d_in[1];
    const float* W_pre  = (const float*)d_in[2];
    const float* b_pre  = (const float*)d_in[3];
    const float* W_fc1  = (const float*)d_in[4];
    const float* b_fc1  = (const float*)d_in[5];
    const float* W_fc2  = (const float*)d_in[6];
    const float* b_fc2  = (const float*)d_in[7];
    const float* W_gcn  = (const float*)d_in[8];
    const float* b_gcn  = (const float*)d_in[9];
    const float* W_dense= (const float*)d_in[10];
    const float* b_dense= (const float*)d_in[11];
    const float* W_f1   = (const float*)d_in[12];
    const float* b_f1   = (const float*)d_in[13];
    const float* W_f2   = (const float*)d_in[14];
    const float* b_f2   = (const float*)d_in[15];

    const int* src = ei;
    const int* dst = ei + NE;

    size_t off = 0;
    auto alloc = [&](size_t bytes) -> void* {
        off = (off + 255) & ~(size_t)255;
        void* p = (char*)d_ws + off;
        off += bytes;
        return p;
    };
    int*   deg     = (int*)  alloc(NN * sizeof(int));
    int*   row_off = (int*)  alloc(NN * sizeof(int));
    int*   blk     = (int*)  alloc(128 * sizeof(int));
    int*   blk_off = (int*)  alloc(128 * sizeof(int));
    float* dis     = (float*)alloc(NN * sizeof(float));
    int*   gcur    = (int*)  alloc(NB * sizeof(int));
    int2*  csr     = (int2*) alloc((size_t)NE * sizeof(int2));
    // bin (12.8 MB) overlays gA+gB (2 x 6.4 MB fp16): bin dead before preproc.
    char*  Ureg    = (char*) alloc(2 * (size_t)NN * 32 * sizeof(_Float16));
    half4* ni      = (half4*)alloc((size_t)NN * 32 * sizeof(_Float16));
    unsigned* bin  = (unsigned*)Ureg;
    half4* gA      = (half4*)Ureg;
    half4* gB      = (half4*)(Ureg + (size_t)NN * 32 * sizeof(_Float16));

    const int scanBlocks  = (NN + 1023) / 1024;   // 98
    const int nodeBlocks  = (NN + 255) / 256;     // 391
    const int binBlocks   = (NE + EPB - 1) / EPB; // 782
    const int fusedBlocks = NN / 32;              // 3125

    k_init_gcur<<<1, 512, 0, stream>>>(gcur);
    k_bin<<<binBlocks, 256, 0, stream>>>(src, dst, gcur, bin);
    k_bucket_deg<<<NB, 1024, 0, stream>>>(gcur, bin, deg);
    k_scan_blocks<<<scanBlocks, 1024, 0, stream>>>(deg, row_off, blk);
    k_scan_tops<<<1, 64, 0, stream>>>(blk, blk_off, scanBlocks);
    k_finalize<<<nodeBlocks, 256, 0, stream>>>(deg, row_off, blk_off, dis);
    k_pass2<<<NB, 1024, 0, stream>>>(gcur, bin, row_off, dis, csr);

    k_preproc<<<fusedBlocks, 256, 0, stream>>>(x, W_pre, b_pre, W_fc1, b_fc1,
                                               W_fc2, b_fc2, W_gcn, ni, gA);

    half4* gin = gA;
    half4* gout = gB;
    for (int l = 0; l < 5; l++) {
        k_layer<false><<<fusedBlocks, 256, 0, stream>>>(
            gin, csr, row_off, deg, dis, ni, W_dense, b_dense, b_gcn,
            W_gcn, nullptr, nullptr, nullptr, (void*)gout);
        half4* tmp = gin; gin = gout; gout = tmp;
    }
    k_layer<true><<<fusedBlocks, 256, 0, stream>>>(
        gin, csr, row_off, deg, dis, ni, W_dense, b_dense, b_gcn,
        W_f1, b_f1, W_f2, b_f2, d_out);
}

// Round 5
// 478.047 us; speedup vs baseline: 2.9953x; 1.0296x over previous
//
#include <hip/hip_runtime.h>
#include <math.h>

#define NN 100000
#define NE 3200000
#define NB 196          // dst-buckets of 512 nodes: 196*512 = 100352 >= NN
#define CAPB 20480      // bin entries per bucket (mean 16327, sigma~128 -> +32 sigma)
#define CAPE 20480      // csr entries per bucket (padded layout, no global scan)
#define EPB 8192        // edges per k_bin slab (512 threads, 16 edges/thread)

typedef _Float16 half4 __attribute__((ext_vector_type(4)));

// ---------------- binned CSR build ----------------

__global__ __launch_bounds__(512) void k_init_gcur(int* gcur) {
    int i = threadIdx.x;
    if (i < NB) gcur[i] = i * CAPB;
}

// Pass 1: bin edges by dst>>9 into per-bucket regions (chunked reservation).
__global__ __launch_bounds__(512) void k_bin(const int* __restrict__ src,
                                             const int* __restrict__ dst,
                                             int* __restrict__ gcur,
                                             unsigned* __restrict__ bin) {
    __shared__ int hist[NB];
    __shared__ int base[NB];
    int tid = threadIdx.x;
    for (int i = tid; i < NB; i += 512) hist[i] = 0;
    __syncthreads();
    int e0 = blockIdx.x * EPB;
    int dcache[EPB / 512];
#pragma unroll
    for (int i = 0; i < EPB / 512; i++) {
        int e = e0 + i * 512 + tid;
        dcache[i] = (e < NE) ? dst[e] : -1;
        if (dcache[i] >= 0) atomicAdd(&hist[dcache[i] >> 9], 1);
    }
    __syncthreads();
    for (int i = tid; i < NB; i += 512) {
        int c = hist[i];
        base[i] = (c > 0) ? atomicAdd(&gcur[i], c) : 0;
    }
    __syncthreads();
    for (int i = tid; i < NB; i += 512) hist[i] = 0;
    __syncthreads();
#pragma unroll
    for (int i = 0; i < EPB / 512; i++) {
        int e = e0 + i * 512 + tid;
        int d = dcache[i];
        if (d >= 0) {
            int b = d >> 9;
            int pos = base[b] + atomicAdd(&hist[b], 1);
            bin[pos] = ((unsigned)src[e] << 9) | (unsigned)(d & 511);
        }
    }
}

// Per-bucket: histogram -> local exclusive scan -> rc=(start,cnt), dis.
// Padded CSR layout (bucket b rows start at b*CAPE) removes the global scan.
__global__ __launch_bounds__(1024) void k_deg_off(const int* __restrict__ gcur,
                                                  const unsigned* __restrict__ bin,
                                                  int2* __restrict__ rc,
                                                  float* __restrict__ dis) {
    __shared__ int hist[512];
    __shared__ int sc[512];
    int b = blockIdx.x, tid = threadIdx.x;
    if (tid < 512) hist[tid] = 0;
    __syncthreads();
    int base = b * CAPB, cnt = gcur[b] - base;
    for (int i = tid; i < cnt; i += 1024) atomicAdd(&hist[bin[base + i] & 511], 1);
    __syncthreads();
    if (tid < 512) sc[tid] = hist[tid];
    __syncthreads();
    for (int off = 1; off < 512; off <<= 1) {
        int t = 0;
        if (tid < 512 && tid >= off) t = sc[tid - off];
        __syncthreads();
        if (tid < 512) sc[tid] += t;
        __syncthreads();
    }
    if (tid < 512) {
        int node = b * 512 + tid;
        if (node < NN) {
            int c = hist[tid];
            rc[node] = make_int2(b * CAPE + sc[tid] - c, c);
            dis[node] = rsqrtf((float)c + 1.0f);
        }
    }
}

// Pass 2: per-bucket scatter with LDS cursors; all writes of a bucket's
// CSR region come from one CU -> lines merge fully in its L2.
__global__ __launch_bounds__(1024) void k_pass2(const int* __restrict__ gcur,
                                                const unsigned* __restrict__ bin,
                                                const int2* __restrict__ rc,
                                                const float* __restrict__ dis,
                                                int2* __restrict__ csr) {
    __shared__ int cur[512];
    __shared__ float sdis[512];
    int b = blockIdx.x, tid = threadIdx.x;
    if (tid < 512) {
        int node = b * 512 + tid;
        if (node < NN) {
            int2 r = rc[node];
            cur[tid] = r.x;
            sdis[tid] = rsqrtf((float)r.y + 1.0f);
        } else { cur[tid] = 0; sdis[tid] = 0.0f; }
    }
    __syncthreads();
    int base = b * CAPB, cnt = gcur[b] - base;
    for (int i = tid; i < cnt; i += 1024) {
        unsigned u = bin[base + i];
        int dl = u & 511;
        int s  = (int)(u >> 9);
        int pos = atomicAdd(&cur[dl], 1);
        float w = dis[s] * sdis[dl];
        csr[pos] = make_int2(s, __float_as_int(w));
    }
}

// ---------------- fused preproc (+ first GCN transform) ----------------
__global__ __launch_bounds__(256) void k_preproc(
        const float* __restrict__ x,
        const float* __restrict__ W_pre, const float* __restrict__ b_pre,
        const float* __restrict__ W_fc1, const float* __restrict__ b_fc1,
        const float* __restrict__ W_fc2, const float* __restrict__ b_fc2,
        const float* __restrict__ W_gcn,
        half4* __restrict__ ni, half4* __restrict__ g_out) {
    __shared__ __align__(16) float sWp[60];
    __shared__ __align__(16) float sbp[12];
    __shared__ __align__(16) float sW1[320];
    __shared__ __align__(16) float sb1[32];
    __shared__ __align__(16) float sW2[320];
    __shared__ __align__(16) float sb2[32];
    __shared__ __align__(16) float sWg[1024];
    __shared__ __align__(16) float s_h[32 * 36];
    int tid = threadIdx.x;
    if (tid < 60) sWp[tid] = W_pre[tid];
    if (tid >= 64 && tid < 74) sbp[tid - 64] = b_pre[tid - 64];
    for (int i = tid; i < 320; i += 256) { sW1[i] = W_fc1[i]; sW2[i] = W_fc2[i]; }
    if (tid >= 96 && tid < 128) sb1[tid - 96] = b_fc1[tid - 96];
    if (tid >= 128 && tid < 160) sb2[tid - 128] = b_fc2[tid - 128];
    for (int i = tid; i < 1024; i += 256) sWg[i] = W_gcn[i];
    __syncthreads();

    int ln = tid >> 3, q = tid & 7;
    int n = blockIdx.x * 32 + ln;

    float xv[6];
#pragma unroll
    for (int k = 0; k < 6; k++) xv[k] = x[n * 6 + k];
    float p[10];
#pragma unroll
    for (int j = 0; j < 10; j++) {
        float a = sbp[j];
#pragma unroll
        for (int k = 0; k < 6; k++) a = fmaf(xv[k], sWp[k * 10 + j], a);
        p[j] = 1.0f / (1.0f + expf(-a));
    }
    float4 a1 = ((const float4*)sb1)[q];
    float4 a2 = ((const float4*)sb2)[q];
#pragma unroll
    for (int k = 0; k < 10; k++) {
        float4 w1 = ((const float4*)sW1)[k * 8 + q];
        float4 w2 = ((const float4*)sW2)[k * 8 + q];
        a1.x = fmaf(p[k], w1.x, a1.x); a1.y = fmaf(p[k], w1.y, a1.y);
        a1.z = fmaf(p[k], w1.z, a1.z); a1.w = fmaf(p[k], w1.w, a1.w);
        a2.x = fmaf(p[k], w2.x, a2.x); a2.y = fmaf(p[k], w2.y, a2.y);
        a2.z = fmaf(p[k], w2.z, a2.z); a2.w = fmaf(p[k], w2.w, a2.w);
    }
    half4 niv;
    niv.x = (_Float16)fmaxf(a1.x, 0.f); niv.y = (_Float16)fmaxf(a1.y, 0.f);
    niv.z = (_Float16)fmaxf(a1.z, 0.f); niv.w = (_Float16)fmaxf(a1.w, 0.f);
    ni[n * 8 + q] = niv;
    float4 hv;
    hv.x = fmaxf(a2.x, 0.f); hv.y = fmaxf(a2.y, 0.f);
    hv.z = fmaxf(a2.z, 0.f); hv.w = fmaxf(a2.w, 0.f);
    *(float4*)&s_h[ln * 36 + 4 * q] = hv;
    __syncthreads();
    float4 o = make_float4(0.f, 0.f, 0.f, 0.f);
#pragma unroll
    for (int k = 0; k < 32; k++) {
        float v = s_h[ln * 36 + k];
        float4 wv = ((const float4*)sWg)[k * 8 + q];
        o.x = fmaf(v, wv.x, o.x); o.y = fmaf(v, wv.y, o.y);
        o.z = fmaf(v, wv.z, o.z); o.w = fmaf(v, wv.w, o.w);
    }
    half4 oh;
    oh.x = (_Float16)o.x; oh.y = (_Float16)o.y;
    oh.z = (_Float16)o.z; oh.w = (_Float16)o.w;
    g_out[n * 8 + q] = oh;
}

// ---------------- fused layer ----------------
template <bool LAST>
__global__ __launch_bounds__(256, 8) void k_layer(
        const half4* __restrict__ g_in,
        const int2* __restrict__ csr,
        const int2* __restrict__ rc,
        const half4* __restrict__ ni,
        const float* __restrict__ W_dense, const float* __restrict__ b_dense,
        const float* __restrict__ b_gcn,
        const float* __restrict__ W2,          // LAST ? W_f1 : W_gcn
        const float* __restrict__ b_f1,
        const float* __restrict__ W_f2, const float* __restrict__ b_f2,
        void* __restrict__ out)                // LAST ? float logits : half4 g_out
{
    __shared__ __align__(16) float sWd[2048];
    __shared__ __align__(16) float sW2[LAST ? 2048 : 1024];
    __shared__ __align__(16) float sbd[32];
    __shared__ __align__(16) float sbg[32];
    __shared__ __align__(16) float sbf1[LAST ? 32 : 4];
    __shared__ __align__(16) float sWf2[LAST ? 64 : 4];
    __shared__ __align__(16) float sbf2[LAST ? 2 : 2];
    __shared__ __align__(16) _Float16 s_ni[32 * 36];   // fp16 staging (lossless)
    __shared__ __align__(16) float s_t[32 * 36];

    int tid = threadIdx.x;
    for (int i = tid; i < 2048; i += 256) sWd[i] = W_dense[i];
    const int n2 = LAST ? 2048 : 1024;
    for (int i = tid; i < n2; i += 256) sW2[i] = W2[i];
    if (tid < 32) { sbd[tid] = b_dense[tid]; sbg[tid] = b_gcn[tid]; }
    if constexpr (LAST) {
        if (tid >= 64 && tid < 96) sbf1[tid - 64] = b_f1[tid - 64];
        if (tid >= 96 && tid < 160) sWf2[tid - 96] = W_f2[tid - 96];
        if (tid >= 160 && tid < 162) sbf2[tid - 160] = b_f2[tid - 160];
    }
    __syncthreads();

    int ln = tid >> 3, q = tid & 7;
    int n = blockIdx.x * 32 + ln;

    // ---- gather (fp16 g rows, 2 batches in flight, branchless tail) ----
    int2 r = rc[n];
    int start = r.x, cnt = r.y;
    float4 acc;
    {
        float d = rsqrtf((float)cnt + 1.0f);
        float sn = d * d;
        half4 gs = g_in[n * 8 + q];
        acc.x = (float)gs.x * sn; acc.y = (float)gs.y * sn;
        acc.z = (float)gs.z * sn; acc.w = (float)gs.w * sn;
    }
    int nbat = (cnt + 7) >> 3;
    const long long* csr8 = (const long long*)csr;
    for (int b = 0; b < nbat; b += 2) {
        int i0 = b * 8 + q, i1 = i0 + 8;
        long long e0 = 0, e1 = 0;
        if (i0 < cnt) e0 = __builtin_nontemporal_load(csr8 + start + i0);
        if (i1 < cnt) e1 = __builtin_nontemporal_load(csr8 + start + i1);
#pragma unroll
        for (int j = 0; j < 8; j++) {
            int   s = __shfl((int)e0, j, 8);
            float w = __int_as_float(__shfl((int)((unsigned long long)e0 >> 32), j, 8));
            half4 gv = g_in[s * 8 + q];
            acc.x = fmaf((float)gv.x, w, acc.x); acc.y = fmaf((float)gv.y, w, acc.y);
            acc.z = fmaf((float)gv.z, w, acc.z); acc.w = fmaf((float)gv.w, w, acc.w);
        }
        if (b + 1 < nbat) {
#pragma unroll
            for (int j = 0; j < 8; j++) {
                int   s = __shfl((int)e1, j, 8);
                float w = __int_as_float(__shfl((int)((unsigned long long)e1 >> 32), j, 8));
                half4 gv = g_in[s * 8 + q];
                acc.x = fmaf((float)gv.x, w, acc.x); acc.y = fmaf((float)gv.y, w, acc.y);
                acc.z = fmaf((float)gv.z, w, acc.z); acc.w = fmaf((float)gv.w, w, acc.w);
            }
        }
    }
    float4 t;
    t.x = fmaxf(acc.x + sbg[4 * q + 0], 0.f);
    t.y = fmaxf(acc.y + sbg[4 * q + 1], 0.f);
    t.z = fmaxf(acc.z + sbg[4 * q + 2], 0.f);
    t.w = fmaxf(acc.w + sbg[4 * q + 3], 0.f);
    *(float4*)&s_t[ln * 36 + 4 * q] = t;
    *(half4*)&s_ni[ln * 36 + 4 * q] = ni[n * 8 + q];
    __syncthreads();

    // ---- dense: h = relu(concat(ni, t) @ W_dense + b_dense) ----
    float4 a = ((const float4*)sbd)[q];
#pragma unroll
    for (int k = 0; k < 32; k++) {
        float v = (float)s_ni[ln * 36 + k];
        float4 wv = ((const float4*)sWd)[k * 8 + q];
        a.x = fmaf(v, wv.x, a.x); a.y = fmaf(v, wv.y, a.y);
        a.z = fmaf(v, wv.z, a.z); a.w = fmaf(v, wv.w, a.w);
    }
#pragma unroll
    for (int k = 0; k < 32; k++) {
        float v = s_t[ln * 36 + k];
        float4 wv = ((const float4*)sWd)[(32 + k) * 8 + q];
        a.x = fmaf(v, wv.x, a.x); a.y = fmaf(v, wv.y, a.y);
        a.z = fmaf(v, wv.z, a.z); a.w = fmaf(v, wv.w, a.w);
    }
    float4 h;
    h.x = fmaxf(a.x, 0.f); h.y = fmaxf(a.y, 0.f);
    h.z = fmaxf(a.z, 0.f); h.w = fmaxf(a.w, 0.f);
    __syncthreads();
    *(float4*)&s_t[ln * 36 + 4 * q] = h;
    __syncthreads();

    if constexpr (!LAST) {
        float4 o = make_float4(0.f, 0.f, 0.f, 0.f);
#pragma unroll
        for (int k = 0; k < 32; k++) {
            float v = s_t[ln * 36 + k];
            float4 wv = ((const float4*)sW2)[k * 8 + q];
            o.x = fmaf(v, wv.x, o.x); o.y = fmaf(v, wv.y, o.y);
            o.z = fmaf(v, wv.z, o.z); o.w = fmaf(v, wv.w, o.w);
        }
        half4 oh;
        oh.x = (_Float16)o.x; oh.y = (_Float16)o.y;
        oh.z = (_Float16)o.z; oh.w = (_Float16)o.w;
        ((half4*)out)[n * 8 + q] = oh;
    } else {
        float4 a2 = ((const float4*)sbf1)[q];
#pragma unroll
        for (int k = 0; k < 32; k++) {
            float v = (float)s_ni[ln * 36 + k];
            float4 wv = ((const float4*)sW2)[k * 8 + q];
            a2.x = fmaf(v, wv.x, a2.x); a2.y = fmaf(v, wv.y, a2.y);
            a2.z = fmaf(v, wv.z, a2.z); a2.w = fmaf(v, wv.w, a2.w);
        }
#pragma unroll
        for (int k = 0; k < 32; k++) {
            float v = s_t[ln * 36 + k];
            float4 wv = ((const float4*)sW2)[(32 + k) * 8 + q];
            a2.x = fmaf(v, wv.x, a2.x); a2.y = fmaf(v, wv.y, a2.y);
            a2.z = fmaf(v, wv.z, a2.z); a2.w = fmaf(v, wv.w, a2.w);
        }
        float4 u;
        u.x = fmaxf(a2.x, 0.f); u.y = fmaxf(a2.y, 0.f);
        u.z = fmaxf(a2.z, 0.f); u.w = fmaxf(a2.w, 0.f);
        float p0 = u.x * sWf2[(4 * q + 0) * 2 + 0] + u.y * sWf2[(4 * q + 1) * 2 + 0]
                 + u.z * sWf2[(4 * q + 2) * 2 + 0] + u.w * sWf2[(4 * q + 3) * 2 + 0];
        float p1 = u.x * sWf2[(4 * q + 0) * 2 + 1] + u.y * sWf2[(4 * q + 1) * 2 + 1]
                 + u.z * sWf2[(4 * q + 2) * 2 + 1] + u.w * sWf2[(4 * q + 3) * 2 + 1];
        p0 += __shfl_down(p0, 4, 8); p1 += __shfl_down(p1, 4, 8);
        p0 += __shfl_down(p0, 2, 8); p1 += __shfl_down(p1, 2, 8);
        p0 += __shfl_down(p0, 1, 8); p1 += __shfl_down(p1, 1, 8);
        if (q == 0) {
            ((float*)out)[n * 2 + 0] = p0 + sbf2[0];
            ((float*)out)[n * 2 + 1] = p1 + sbf2[1];
        }
    }
}

// ---------------- launch ----------------

extern "C" void kernel_launch(void* const* d_in, const int* in_sizes, int n_in,
                              void* d_out, int out_size, void* d_ws, size_t ws_size,
                              hipStream_t stream) {
    const float* x      = (const float*)d_in[0];
    const int*   ei     = (const int*)d_in[1];
    const float* W_pre  = (const float*)d_in[2];
    const float* b_pre  = (const float*)d_in[3];
    const float* W_fc1  = (const float*)d_in[4];
    const float* b_fc1  = (const float*)d_in[5];
    const float* W_fc2  = (const float*)d_in[6];
    const float* b_fc2  = (const float*)d_in[7];
    const float* W_gcn  = (const float*)d_in[8];
    const float* b_gcn  = (const float*)d_in[9];
    const float* W_dense= (const float*)d_in[10];
    const float* b_dense= (const float*)d_in[11];
    const float* W_f1   = (const float*)d_in[12];
    const float* b_f1   = (const float*)d_in[13];
    const float* W_f2   = (const float*)d_in[14];
    const float* b_f2   = (const float*)d_in[15];

    const int* src = ei;
    const int* dst = ei + NE;

    size_t off = 0;
    auto alloc = [&](size_t bytes) -> void* {
        off = (off + 255) & ~(size_t)255;
        void* p = (char*)d_ws + off;
        off += bytes;
        return p;
    };
    int2*  rc      = (int2*) alloc((size_t)NN * sizeof(int2));
    float* dis     = (float*)alloc(NN * sizeof(float));
    int*   gcur    = (int*)  alloc(NB * sizeof(int));
    int2*  csr     = (int2*) alloc((size_t)NB * CAPE * sizeof(int2));   // 32.1 MB padded
    // bin (16.1 MB) overlays gA+gB (2 x 6.4 MB fp16): bin dead before preproc.
    char*  Ureg    = (char*) alloc((size_t)NB * CAPB * sizeof(unsigned));
    half4* ni      = (half4*)alloc((size_t)NN * 32 * sizeof(_Float16));
    unsigned* bin  = (unsigned*)Ureg;
    half4* gA      = (half4*)Ureg;
    half4* gB      = (half4*)(Ureg + (size_t)NN * 32 * sizeof(_Float16));

    const int binBlocks   = (NE + EPB - 1) / EPB; // 391
    const int fusedBlocks = NN / 32;              // 3125

    k_init_gcur<<<1, 512, 0, stream>>>(gcur);
    k_bin<<<binBlocks, 512, 0, stream>>>(src, dst, gcur, bin);
    k_deg_off<<<NB, 1024, 0, stream>>>(gcur, bin, rc, dis);
    k_pass2<<<NB, 1024, 0, stream>>>(gcur, bin, rc, dis, csr);

    k_preproc<<<fusedBlocks, 256, 0, stream>>>(x, W_pre, b_pre, W_fc1, b_fc1,
                                               W_fc2, b_fc2, W_gcn, ni, gA);

    half4* gin = gA;
    half4* gout = gB;
    for (int l = 0; l < 5; l++) {
        k_layer<false><<<fusedBlocks, 256, 0, stream>>>(
            gin, csr, rc, ni, W_dense, b_dense, b_gcn,
            W_gcn, nullptr, nullptr, nullptr, (void*)gout);
        half4* tmp = gin; gin = gout; gout = tmp;
    }
    k_layer<true><<<fusedBlocks, 256, 0, stream>>>(
        gin, csr, rc, ni, W_dense, b_dense, b_gcn,
        W_f1, b_f1, W_f2, b_f2, d_out);
}